// Round 9
// baseline (36.717 us; speedup 1.0000x reference)
//
#include <hip/hip_runtime.h>

#define NR_ACTIONS 64
#define VEC 512
#define CH_K 128            // K per chunk
#define BPITCH 136          // ushort pitch per col (128+8) = 272 B, 16B-aligned
#define MAXB 2048           // fast-scan path size

typedef short bf16x8 __attribute__((ext_vector_type(8)));
typedef float f32x4  __attribute__((ext_vector_type(4)));

__device__ __forceinline__ ushort f2bf(float f) {
    union { float f; uint32_t u; } x; x.f = f;
    uint32_t r = x.u + 0x7FFFu + ((x.u >> 16) & 1u);   // RNE
    return (ushort)(r >> 16);
}
__device__ __forceinline__ uint32_t pack2(float a, float b) {
    return (uint32_t)f2bf(a) | ((uint32_t)f2bf(b) << 16);
}

// issue 8 independent float4 W-loads for chunk ck (cols j0.., k-local per lane)
__device__ __forceinline__ void loadw(const float* __restrict__ Wa, int ck, int lane,
                                      float4 wr[8]) {
    const float* p = Wa + (size_t)(ck * CH_K + (lane >> 2) * 8) * VEC + (lane & 3) * 4;
#pragma unroll
    for (int i = 0; i < 8; ++i) wr[i] = *(const float4*)(p + (size_t)i * VEC);
}
// cvt + transposed write: sbuf[col*BPITCH + klocal] bf16 (conflict-free b128 writes)
__device__ __forceinline__ void cvtwrite(const float4 wr[8], ushort* sbuf, int lane) {
    const int kq = (lane >> 2) * 8;
#pragma unroll
    for (int c = 0; c < 4; ++c) {
        const int col = (lane & 3) * 4 + c;
        uint4 p;
        p.x = pack2((&wr[0].x)[c], (&wr[1].x)[c]);
        p.y = pack2((&wr[2].x)[c], (&wr[3].x)[c]);
        p.z = pack2((&wr[4].x)[c], (&wr[5].x)[c]);
        p.w = pack2((&wr[6].x)[c], (&wr[7].x)[c]);
        *(uint4*)&sbuf[col * BPITCH + kq] = p;
    }
}
// A-fragments for one chunk, both rowblocks, fp32 -> bf16 in-register
__device__ __forceinline__ void loada(const float* __restrict__ v,
                                      int r0, int r1, int ck, int g, bf16x8 ar[2][4]) {
    const float* a0 = v + (size_t)r0 * VEC + ck * CH_K + g * 8;
    const float* a1 = v + (size_t)r1 * VEC + ck * CH_K + g * 8;
#pragma unroll
    for (int rb = 0; rb < 2; ++rb) {
        const float* ap = rb ? a1 : a0;
#pragma unroll
        for (int ks = 0; ks < 4; ++ks) {
            const float4 f0 = *(const float4*)(ap + ks * 32);
            const float4 f1 = *(const float4*)(ap + ks * 32 + 4);
            union { uint32_t u[4]; bf16x8 s; } au;
            au.u[0] = pack2(f0.x, f0.y); au.u[1] = pack2(f0.z, f0.w);
            au.u[2] = pack2(f1.x, f1.y); au.u[3] = pack2(f1.z, f1.w);
            ar[rb][ks] = au.s;
        }
    }
}
__device__ __forceinline__ void compute_chunk(const ushort* sbuf, int lane, int g,
                                              const bf16x8 ar[2][4],
                                              f32x4& acc0, f32x4& acc1) {
#pragma unroll
    for (int ks = 0; ks < 4; ++ks) {
        const bf16x8 bf = *(const bf16x8*)&sbuf[(lane & 15) * BPITCH + ks * 32 + g * 8];
        acc0 = __builtin_amdgcn_mfma_f32_16x16x32_bf16(ar[0][ks], bf, acc0, 0, 0, 0);
        acc1 = __builtin_amdgcn_mfma_f32_16x16x32_bf16(ar[1][ks], bf, acc1, 0, 0, 0);
    }
}

// ---- single fused kernel: 512 blocks x 4 waves; each WAVE = one (action, 16-col)
// tile, K pipelined in 4 chunks through wave-private dbuf LDS. One barrier total.
// A-operand converted fp32->bf16 in-register (no prep kernel, no workspace). ----
__global__ __launch_bounds__(256, 2) void grouped_fused(
    const float* __restrict__ v, const int* __restrict__ action,
    const float* __restrict__ W, float* __restrict__ out, int batch)
{
    __shared__ ushort sB[4][2][16 * BPITCH];   // 34.8 KB: wave-private dbuf pairs
    __shared__ ushort slist[MAXB];             // 4 KB ordered group list
    __shared__ int    smc;

    const int p    = blockIdx.x;
    const int a    = p >> 3;                   // 8 blocks per action
    const int tid  = threadIdx.x;
    const int lane = tid & 63;
    const int wv   = tid >> 6;
    const int j0   = ((p & 7) * 4 + wv) * 16;  // this wave's 16-col tile

    const float* Wa = W + (size_t)a * VEC * VEC + j0;
    const bool fast = (batch == MAXB);

    // wave0: issue independent action loads first (vmcnt in-order per wave)
    int av[32];
    if (wv == 0 && fast) {
#pragma unroll
        for (int c = 0; c < 32; ++c) av[c] = action[c * 64 + lane];
    }

    // staging prologue: chunks 0,1 in flight
    float4 wrA[8], wrB[8];
    loadw(Wa, 0, lane, wrA);
    loadw(Wa, 1, lane, wrB);

    // wave0: ordered full-group list (register-only ballot chain on fast path)
    if (wv == 0) {
        int base = 0;
        if (fast) {
#pragma unroll
            for (int c = 0; c < 32; ++c) {
                const bool hit = (av[c] == a);
                const unsigned long long mk = __ballot(hit);
                const int pos = base + __popcll(mk & ((1ull << lane) - 1ull));
                if (hit) slist[pos] = (ushort)(c * 64 + lane);
                base += __popcll(mk);
            }
        } else {
            for (int it = 0; it < batch; it += 64) {
                const int idx = it + lane;
                const bool hit = (idx < batch) && (action[idx] == a);
                const unsigned long long mk = __ballot(hit);
                const int pos = base + __popcll(mk & ((1ull << lane) - 1ull));
                if (hit && pos < MAXB) slist[pos] = (ushort)idx;
                base += __popcll(mk);
            }
        }
        if (lane == 0) smc = base;
    }

    ushort* b0 = &sB[wv][0][0];
    ushort* b1 = &sB[wv][1][0];
    cvtwrite(wrA, b0, lane);        // chunk0 -> buf0 (waits only its own loads)

    __syncthreads();                // the ONLY block barrier: slist/smc published
    const int m = smc;
    if (m == 0) return;

    const int g    = lane >> 4;
    const int colg = j0 + (lane & 15);
    bf16x8 ar[2][4];

    for (int wlo = 0; wlo < m; wlo += 32) {
        const int mw = min(32, m - wlo);
        const int i0 = wlo + (lane & 15);
        const int i1 = wlo + 16 + (lane & 15);
        const int r0 = slist[i0 < m ? i0 : wlo];
        const int r1 = slist[i1 < m ? i1 : wlo];

        if (wlo > 0) {              // rare: restage chunks 0,1 for next window
            loadw(Wa, 0, lane, wrA);
            loadw(Wa, 1, lane, wrB);
            cvtwrite(wrA, b0, lane);
        }
        loada(v, r0, r1, 0, g, ar);
        loadw(Wa, 2, lane, wrA);

        f32x4 acc0 = {0.f, 0.f, 0.f, 0.f}, acc1 = {0.f, 0.f, 0.f, 0.f};
        // c=0
        compute_chunk(b0, lane, g, ar, acc0, acc1);
        cvtwrite(wrB, b1, lane);            // chunk1
        loada(v, r0, r1, 1, g, ar);
        loadw(Wa, 3, lane, wrB);
        // c=1
        compute_chunk(b1, lane, g, ar, acc0, acc1);
        cvtwrite(wrA, b0, lane);            // chunk2
        loada(v, r0, r1, 2, g, ar);
        // c=2
        compute_chunk(b0, lane, g, ar, acc0, acc1);
        cvtwrite(wrB, b1, lane);            // chunk3
        loada(v, r0, r1, 3, g, ar);
        // c=3
        compute_chunk(b1, lane, g, ar, acc0, acc1);

        // D layout: col=lane&15, row=(lane>>4)*4+q (m89-verified)
#pragma unroll
        for (int q = 0; q < 4; ++q) {
            const int o0 = g * 4 + q;
            if (o0 < mw) out[(size_t)slist[wlo + o0] * VEC + colg] = acc0[q];
            const int o1 = 16 + g * 4 + q;
            if (o1 < mw) out[(size_t)slist[wlo + o1] * VEC + colg] = acc1[q];
        }
    }
}

// ---- fallback for batch > MAXB: naive per-row ----
__global__ void naive_vm(const float* __restrict__ v, const float* __restrict__ W,
                         const int* __restrict__ action, float* __restrict__ out) {
    const int b = blockIdx.x;
    const int a = action[b];
    const float* wbase = W + (size_t)a * VEC * VEC;
    const float* vb = v + (size_t)b * VEC;
    const int j = threadIdx.x;
    float acc0 = 0.f, acc1 = 0.f;
    for (int k = 0; k < VEC; ++k) {
        const float vk = vb[k];
        acc0 = fmaf(vk, wbase[(size_t)k * VEC + j], acc0);
        acc1 = fmaf(vk, wbase[(size_t)k * VEC + j + 256], acc1);
    }
    out[(size_t)b * VEC + j] = acc0;
    out[(size_t)b * VEC + j + 256] = acc1;
}

extern "C" void kernel_launch(void* const* d_in, const int* in_sizes, int n_in,
                              void* d_out, int out_size, void* d_ws, size_t ws_size,
                              hipStream_t stream) {
    const float* v      = (const float*)d_in[0];
    const int*   action = (const int*)d_in[1];
    const float* W      = (const float*)d_in[2];
    float* out = (float*)d_out;
    const int batch = in_sizes[1];
    if (batch <= 0) return;

    if (batch <= MAXB) {
        const int nblocks = NR_ACTIONS * 8;   // 512: 8 blocks/action x 4 wave-tiles
        grouped_fused<<<nblocks, 256, 0, stream>>>(v, action, W, out, batch);
    } else {
        naive_vm<<<batch, 256, 0, stream>>>(v, W, action, out);
    }
}

// Round 10
// 33.517 us; speedup vs baseline: 1.0955x; 1.0955x over previous
//
#include <hip/hip_runtime.h>

#define NR_ACTIONS 64
#define VEC 512
#define CH 128              // K per pipeline chunk
#define MAXB 2048           // fast-scan path size

typedef short bf16x8 __attribute__((ext_vector_type(8)));
typedef float f32x4  __attribute__((ext_vector_type(4)));

__device__ __forceinline__ ushort f2bf(float f) {
    union { float f; uint32_t u; } x; x.f = f;
    uint32_t r = x.u + 0x7FFFu + ((x.u >> 16) & 1u);   // RNE
    return (ushort)(r >> 16);
}
__device__ __forceinline__ uint32_t pack2(float a, float b) {
    return (uint32_t)f2bf(a) | ((uint32_t)f2bf(b) << 16);
}

// ---- prep: v fp32 -> bf16 once ----
__global__ __launch_bounds__(256) void cvt_v_kernel(const float* __restrict__ v,
                                                    ushort* __restrict__ vbf, int n8) {
    const int i = blockIdx.x * 256 + threadIdx.x;
    if (i < n8) {
        const float4 x = ((const float4*)v)[2 * i];
        const float4 y = ((const float4*)v)[2 * i + 1];
        uint4 o;
        o.x = pack2(x.x, x.y); o.y = pack2(x.z, x.w);
        o.z = pack2(y.x, y.y); o.w = pack2(y.z, y.w);
        ((uint4*)vbf)[i] = o;
    }
}

// swizzled byte offset in a 4 KB chunk buffer: col (0..15), kl (0..127)
__device__ __forceinline__ int bswz(int col, int kl) {
    return (col * 256 + kl * 2) ^ ((col & 7) << 4);
}

// 8 independent float4 W loads for chunk ck: col=(l&3)*4.., k=ck*128+(l>>2)*8+i
__device__ __forceinline__ void loadw(const float* __restrict__ Wa, int ck, int lane,
                                      float4 wr[8]) {
    const float* p = Wa + (size_t)(ck * CH + (lane >> 2) * 8) * VEC + (lane & 3) * 4;
#pragma unroll
    for (int i = 0; i < 8; ++i) wr[i] = *(const float4*)(p + (size_t)i * VEC);
}
// cvt + transposed swizzled write into 4 KB chunk buffer
__device__ __forceinline__ void cvtwrite(const float4 wr[8], char* buf, int lane) {
    const int kq = (lane >> 2) * 8;
#pragma unroll
    for (int c = 0; c < 4; ++c) {
        const int col = (lane & 3) * 4 + c;
        uint4 p;
        p.x = pack2((&wr[0].x)[c], (&wr[1].x)[c]);
        p.y = pack2((&wr[2].x)[c], (&wr[3].x)[c]);
        p.z = pack2((&wr[4].x)[c], (&wr[5].x)[c]);
        p.w = pack2((&wr[6].x)[c], (&wr[7].x)[c]);
        *(uint4*)(buf + bswz(col, kq)) = p;
    }
}
// A-fragments for one chunk (this lane's row), bf16 path
__device__ __forceinline__ void loada_bf(const ushort* __restrict__ vrow, int ck, int g,
                                         bf16x8 ar[4]) {
    const ushort* p = vrow + ck * CH + g * 8;
#pragma unroll
    for (int ks = 0; ks < 4; ++ks) ar[ks] = *(const bf16x8*)(p + ks * 32);
}
// A-fragments, fp32 fallback path (in-register cvt)
__device__ __forceinline__ void loada_f32(const float* __restrict__ vrow, int ck, int g,
                                          bf16x8 ar[4]) {
    const float* p = vrow + ck * CH + g * 8;
#pragma unroll
    for (int ks = 0; ks < 4; ++ks) {
        const float4 f0 = *(const float4*)(p + ks * 32);
        const float4 f1 = *(const float4*)(p + ks * 32 + 4);
        union { uint32_t u[4]; bf16x8 s; } au;
        au.u[0] = pack2(f0.x, f0.y); au.u[1] = pack2(f0.z, f0.w);
        au.u[2] = pack2(f1.x, f1.y); au.u[3] = pack2(f1.z, f1.w);
        ar[ks] = au.s;
    }
}
__device__ __forceinline__ void compute(const char* buf, int lane, int g,
                                        const bf16x8 ar[4], f32x4& acc) {
    const int c = lane & 15;
#pragma unroll
    for (int ks = 0; ks < 4; ++ks) {
        const bf16x8 bf = *(const bf16x8*)(buf + bswz(c, ks * 32 + g * 8));
        acc = __builtin_amdgcn_mfma_f32_16x16x32_bf16(ar[ks], bf, acc, 0, 0, 0);
    }
}

// slow-path ordered scan for window [w0, w0+16); returns m
__device__ __forceinline__ int scan_slow(const int* __restrict__ action, int batch,
                                         int a, int w0, int lane, ushort* slist) {
    int base = 0;
    for (int it = 0; it < batch; it += 64) {
        const int idx = it + lane;
        const bool hit = (idx < batch) && (action[idx] == a);
        const unsigned long long mk = __ballot(hit);
        const int rp = base + __popcll(mk & ((1ull << lane) - 1ull)) - w0;
        if (hit && rp >= 0 && rp < 16) slist[rp] = (ushort)idx;
        base += __popcll(mk);
    }
    return base;
}

// ---- main: 6144 blocks x 64 threads (1 wave). Tile = (action, 16 cols, 16 rows).
// Zero barriers; W and A both prefetched 2 chunks ahead; counted vmcnt by compiler.
template <bool BF>
__global__ __launch_bounds__(64, 3) void grouped_wave(
    const float* __restrict__ v, const ushort* __restrict__ vbf,
    const int* __restrict__ action, const float* __restrict__ W,
    float* __restrict__ out, int batch)
{
    __shared__ char   buf0[4096];
    __shared__ char   buf1[4096];
    __shared__ ushort slist[16];

    const int h  = blockIdx.x;
    const int s  = (h & 7) * ((int)gridDim.x >> 3) + (h >> 3);  // XCD-bijective
    const int rb = s % 3;                 // rowblock (0..2), siblings adjacent on XCD
    const int cb = (s / 3) & 31;          // column block
    const int a  = s / 96;                // action
    const int j0 = cb * 16;
    const int lane = threadIdx.x;
    const int g    = lane >> 4;
    const int li   = lane & 15;

    const float* Wa = W + (size_t)a * VEC * VEC + j0;
    const bool fast = (batch == MAXB);

    // ---- prologue: action loads first, then W chunks 0,1 (all fire-and-forget) ----
    int av[32];
    if (fast) {
#pragma unroll
        for (int c = 0; c < 32; ++c) av[c] = action[c * 64 + lane];
    }
    float4 W0r[8], W1r[8];
    loadw(Wa, 0, lane, W0r);
    loadw(Wa, 1, lane, W1r);

    // ---- ordered ballot scan for window rb*16 (register-only on fast path) ----
    int m = 0;
    if (fast) {
#pragma unroll
        for (int c = 0; c < 32; ++c) {
            const bool hit = (av[c] == a);
            const unsigned long long mk = __ballot(hit);
            const int rp = m + __popcll(mk & ((1ull << lane) - 1ull)) - rb * 16;
            if (hit && rp >= 0 && rp < 16) slist[rp] = (ushort)(c * 64 + lane);
            m += __popcll(mk);
        }
    } else {
        m = scan_slow(action, batch, a, rb * 16, lane, slist);
    }

    bool first = true;
    for (int w0 = rb * 16; w0 < m; w0 += 48) {
        if (!first) {                      // rare tail (m > 48): rescan + restage
            scan_slow(action, batch, a, w0, lane, slist);
            loadw(Wa, 0, lane, W0r);
            loadw(Wa, 1, lane, W1r);
        }
        first = false;
        const int mw = min(16, m - w0);

        const int ridx = slist[li < mw ? li : 0];
        const ushort* vrowb = BF ? vbf + (size_t)ridx * VEC : (const ushort*)nullptr;
        const float*  vrowf = BF ? (const float*)nullptr : v + (size_t)ridx * VEC;

        bf16x8 A0[4], A1[4], A2[4], A3[4];
        if (BF) { loada_bf(vrowb, 0, g, A0); loada_bf(vrowb, 1, g, A1); }
        else    { loada_f32(vrowf, 0, g, A0); loada_f32(vrowf, 1, g, A1); }

        cvtwrite(W0r, buf0, lane);         // W0r landed (issued ~scan ago)

        // c0: issue chunk2, compute chunk0
        float4 W2r[8]; loadw(Wa, 2, lane, W2r);
        if (BF) loada_bf(vrowb, 2, g, A2); else loada_f32(vrowf, 2, g, A2);
        f32x4 acc = {0.f, 0.f, 0.f, 0.f};
        compute(buf0, lane, g, A0, acc);
        cvtwrite(W1r, buf1, lane);
        // c1: issue chunk3, compute chunk1
        float4 W3r[8]; loadw(Wa, 3, lane, W3r);
        if (BF) loada_bf(vrowb, 3, g, A3); else loada_f32(vrowf, 3, g, A3);
        compute(buf1, lane, g, A1, acc);
        cvtwrite(W2r, buf0, lane);
        // c2
        compute(buf0, lane, g, A2, acc);
        cvtwrite(W3r, buf1, lane);
        // c3
        compute(buf1, lane, g, A3, acc);

        // D layout: col=lane&15, row=(lane>>4)*4+q (m89-verified)
#pragma unroll
        for (int q = 0; q < 4; ++q) {
            const int row = g * 4 + q;
            if (row < mw)
                out[(size_t)slist[row] * VEC + j0 + li] = acc[q];
        }
    }
}

// ---- fallback for batch > MAXB: naive per-row ----
__global__ void naive_vm(const float* __restrict__ v, const float* __restrict__ W,
                         const int* __restrict__ action, float* __restrict__ out) {
    const int b = blockIdx.x;
    const int a = action[b];
    const float* wbase = W + (size_t)a * VEC * VEC;
    const float* vb = v + (size_t)b * VEC;
    const int j = threadIdx.x;
    float acc0 = 0.f, acc1 = 0.f;
    for (int k = 0; k < VEC; ++k) {
        const float vk = vb[k];
        acc0 = fmaf(vk, wbase[(size_t)k * VEC + j], acc0);
        acc1 = fmaf(vk, wbase[(size_t)k * VEC + j + 256], acc1);
    }
    out[(size_t)b * VEC + j] = acc0;
    out[(size_t)b * VEC + j + 256] = acc1;
}

extern "C" void kernel_launch(void* const* d_in, const int* in_sizes, int n_in,
                              void* d_out, int out_size, void* d_ws, size_t ws_size,
                              hipStream_t stream) {
    const float* v      = (const float*)d_in[0];
    const int*   action = (const int*)d_in[1];
    const float* W      = (const float*)d_in[2];
    float* out = (float*)d_out;
    const int batch = in_sizes[1];
    if (batch <= 0) return;

    if (batch > MAXB) {
        naive_vm<<<batch, 256, 0, stream>>>(v, W, action, out);
        return;
    }
    const int nblocks = NR_ACTIONS * 32 * 3;   // 6144 (%8==0 for XCD swizzle)
    const size_t need = (size_t)batch * VEC * sizeof(ushort);

    if (ws_size >= need && ((size_t)batch * VEC) % 8 == 0) {
        ushort* vbf = (ushort*)d_ws;
        const int n8 = (int)((size_t)batch * VEC / 8);
        cvt_v_kernel<<<(n8 + 255) / 256, 256, 0, stream>>>(v, vbf, n8);
        grouped_wave<true><<<nblocks, 64, 0, stream>>>(v, vbf, action, W, out, batch);
    } else {
        grouped_wave<false><<<nblocks, 64, 0, stream>>>(v, (const ushort*)nullptr,
                                                        action, W, out, batch);
    }
}

// Round 11
// 33.125 us; speedup vs baseline: 1.1084x; 1.0118x over previous
//
#include <hip/hip_runtime.h>

#define NR_ACTIONS 64
#define VEC 512
#define MAXB 2048           // fast-scan path size

typedef short bf16x8 __attribute__((ext_vector_type(8)));
typedef float f32x4  __attribute__((ext_vector_type(4)));

__device__ __forceinline__ ushort f2bf(float f) {
    union { float f; uint32_t u; } x; x.f = f;
    uint32_t r = x.u + 0x7FFFu + ((x.u >> 16) & 1u);   // RNE
    return (ushort)(r >> 16);
}
__device__ __forceinline__ uint32_t pack2(float a, float b) {
    return (uint32_t)f2bf(a) | ((uint32_t)f2bf(b) << 16);
}

// ---- prep: v fp32 -> bf16 once ----
__global__ __launch_bounds__(256) void cvt_v_kernel(const float* __restrict__ v,
                                                    ushort* __restrict__ vbf, int n8) {
    const int i = blockIdx.x * 256 + threadIdx.x;
    if (i < n8) {
        const float4 x = ((const float4*)v)[2 * i];
        const float4 y = ((const float4*)v)[2 * i + 1];
        uint4 o;
        o.x = pack2(x.x, x.y); o.y = pack2(x.z, x.w);
        o.z = pack2(y.x, y.y); o.w = pack2(y.z, y.w);
        ((uint4*)vbf)[i] = o;
    }
}

// ordered wave-level ballot scan (slow path / rare windows): window [w0,w0+64)
__device__ __forceinline__ int scan_win(const int* __restrict__ action, int batch,
                                        int a, int w0, int lane, ushort* slist) {
    int base = 0;
    for (int it = 0; it < batch; it += 64) {
        const int idx = it + lane;
        const bool hit = (idx < batch) && (action[idx] == a);
        const unsigned long long mk = __ballot(hit);
        const int rp = base + __popcll(mk & ((1ull << lane) - 1ull)) - w0;
        if (hit && rp >= 0 && rp < 64) slist[rp] = (ushort)idx;
        base += __popcll(mk);
    }
    return base;
}

// one wave's 16-row sub-block of a <=64-row window against one staged fp32 tile.
// No stores, no barriers: acc returned in regs. active => wstart < mw.
template <bool BF>
__device__ __forceinline__ f32x4 compute_tile(
    const float* __restrict__ sW, const float* __restrict__ v,
    const ushort* __restrict__ vbf, const ushort* slist,
    int mw, int wstart, int lane) {
    const int li = lane & 15;
    const int g  = lane >> 4;
    const int rl = wstart + li;
    const int ridx = slist[rl < mw ? rl : wstart];   // clamp: discarded at store
    f32x4 acc = {0.f, 0.f, 0.f, 0.f};
#pragma unroll
    for (int ks = 0; ks < 16; ++ks) {
        bf16x8 bfrag;
#pragma unroll
        for (int e = 0; e < 8; ++e) {
            const int kk = ks * 32 + g * 8 + e;
            bfrag[e] = (short)f2bf(sW[kk * 16 + li]);
        }
        bf16x8 afrag;
        if (BF) {
            afrag = *(const bf16x8*)(vbf + (size_t)ridx * VEC + ks * 32 + g * 8);
        } else {
            const float* ap = v + (size_t)ridx * VEC + ks * 32 + g * 8;
            float avv[8];
            *(float4*)&avv[0] = *(const float4*)(ap);
            *(float4*)&avv[4] = *(const float4*)(ap + 4);
#pragma unroll
            for (int e = 0; e < 8; ++e) afrag[e] = (short)f2bf(avv[e]);
        }
        acc = __builtin_amdgcn_mfma_f32_16x16x32_bf16(afrag, bfrag, acc, 0, 0, 0);
    }
    return acc;
}

// ---- main: 1024 blocks x 4 waves; block = (action, 32-col pair) = TWO 16-col
// tiles sharing one scan. Depth-2 staging: both tiles' global_load_lds issued
// up-front; counted vmcnt + raw s_barrier keeps tile1's loads in flight across
// tile0's compute (no __syncthreads drain on the hot path). ----
template <bool BF>
__global__ __launch_bounds__(256) void grouped2(
    const float* __restrict__ v, const ushort* __restrict__ vbf,
    const int* __restrict__ action, const float* __restrict__ W,
    float* __restrict__ out, int batch)
{
    __shared__ float  sW0[16 * VEC];   // 32 KB fp32 [k][16], tile0
    __shared__ float  sW1[16 * VEC];   // 32 KB fp32 [k][16], tile1
    __shared__ ushort slist[64];
    __shared__ int    smc;

    const int h    = blockIdx.x;
    const int l    = (h & 7) * ((int)gridDim.x >> 3) + (h >> 3);  // XCD-bijective (1024%8==0)
    const int a    = l >> 4;                  // action (8 whole actions per XCD)
    const int j0   = (l & 15) * 32;           // col-pair base
    const int tid  = threadIdx.x;
    const int lane = tid & 63;
    const int wv   = tid >> 6;

    const float* Wa = W + (size_t)a * VEC * VEC + j0;
    const bool fast = (batch == MAXB);

    // wave0: issue independent action loads FIRST (vmcnt in-order per wave)
    int av[32];
    if (wv == 0 && fast) {
#pragma unroll
        for (int c = 0; c < 32; ++c) av[c] = action[c * 64 + lane];
    }

    // fire-and-forget: tile0 then tile1 (8 calls each per wave, 16 KB/wave in flight)
    {
        const int col4 = (lane & 3) * 4;
        const int krow = lane >> 2;
#pragma unroll
        for (int c = 0; c < 8; ++c) {
            const int kr = (wv * 8 + c) * 16 + krow;
            __builtin_amdgcn_global_load_lds(
                (const __attribute__((address_space(1))) void*)(Wa + (size_t)kr * VEC + col4),
                (__attribute__((address_space(3))) void*)&sW0[(wv * 8 + c) * 256],
                16, 0, 0);
        }
#pragma unroll
        for (int c = 0; c < 8; ++c) {
            const int kr = (wv * 8 + c) * 16 + krow;
            __builtin_amdgcn_global_load_lds(
                (const __attribute__((address_space(1))) void*)(Wa + 16 + (size_t)kr * VEC + col4),
                (__attribute__((address_space(3))) void*)&sW1[(wv * 8 + c) * 256],
                16, 0, 0);
        }
    }

    // wave0: ordered window-0 list (register-only ballot chain on fast path)
    if (wv == 0) {
        if (fast) {
            int base = 0;
#pragma unroll
            for (int c = 0; c < 32; ++c) {
                const bool hit = (av[c] == a);
                const unsigned long long mk = __ballot(hit);
                const int pos = base + __popcll(mk & ((1ull << lane) - 1ull));
                if (hit && pos < 64) slist[pos] = (ushort)(c * 64 + lane);
                base += __popcll(mk);
            }
            if (lane == 0) smc = base;
        } else {
            const int base = scan_win(action, batch, a, 0, lane, slist);
            if (lane == 0) smc = base;
        }
    }

    // Barrier 1: tile0 landed (vmcnt(8) leaves tile1's 8 calls in flight) +
    // slist/smc published. Raw s_barrier: NO full vmcnt drain.
    asm volatile("s_waitcnt vmcnt(8) lgkmcnt(0)\n\ts_barrier" ::: "memory");

    const int m = smc;                 // block-uniform
    if (m == 0) return;                // uniform exit; no further barriers needed

    const int li = lane & 15;
    const int g  = lane >> 4;

    if (m <= 64) {                     // common case (binomial m~32): ONE window
        const int wstart = wv * 16;
        const bool act = wstart < m;
        f32x4 acc0 = {0.f, 0.f, 0.f, 0.f};
        if (act) acc0 = compute_tile<BF>(sW0, v, vbf, slist, m, wstart, lane);

        // Barrier 2: tile1 ready (its loads arrived during tile0's compute).
        asm volatile("s_waitcnt vmcnt(0) lgkmcnt(0)\n\ts_barrier" ::: "memory");

        f32x4 acc1 = {0.f, 0.f, 0.f, 0.f};
        if (act) acc1 = compute_tile<BF>(sW1, v, vbf, slist, m, wstart, lane);

        // deferred stores (overlap nothing critical; D layout m89-verified)
        if (act) {
#pragma unroll
            for (int q = 0; q < 4; ++q) {
                const int row = wstart + g * 4 + q;
                if (row < m) {
                    float* op = out + (size_t)slist[row] * VEC + j0 + li;
                    op[0]  = acc0[q];
                    op[16] = acc1[q];
                }
            }
        }
    } else {
        // rare path (m > 64): plain barrier-per-window loop, block-uniform
        for (int tt = 0; tt < 2; ++tt) {
            const float* sW = tt ? sW1 : sW0;
            for (int wlo = 0; wlo < m; wlo += 64) {
                __syncthreads();           // also drains vmcnt -> sW1 safe at tt=1
                if (wv == 0) scan_win(action, batch, a, wlo, lane, slist);
                __syncthreads();
                const int mw = min(64, m - wlo);
                const int wstart = wv * 16;
                if (wstart < mw) {
                    const f32x4 acc =
                        compute_tile<BF>(sW, v, vbf, slist, mw, wstart, lane);
#pragma unroll
                    for (int q = 0; q < 4; ++q) {
                        const int row = wstart + g * 4 + q;
                        if (row < mw)
                            out[(size_t)slist[row] * VEC + j0 + tt * 16 + li] = acc[q];
                    }
                }
            }
        }
    }
}

// ---- fallback for batch > MAXB: naive per-row ----
__global__ void naive_vm(const float* __restrict__ v, const float* __restrict__ W,
                         const int* __restrict__ action, float* __restrict__ out) {
    const int b = blockIdx.x;
    const int a = action[b];
    const float* wbase = W + (size_t)a * VEC * VEC;
    const float* vb = v + (size_t)b * VEC;
    const int j = threadIdx.x;
    float acc0 = 0.f, acc1 = 0.f;
    for (int k = 0; k < VEC; ++k) {
        const float vk = vb[k];
        acc0 = fmaf(vk, wbase[(size_t)k * VEC + j], acc0);
        acc1 = fmaf(vk, wbase[(size_t)k * VEC + j + 256], acc1);
    }
    out[(size_t)b * VEC + j] = acc0;
    out[(size_t)b * VEC + j + 256] = acc1;
}

extern "C" void kernel_launch(void* const* d_in, const int* in_sizes, int n_in,
                              void* d_out, int out_size, void* d_ws, size_t ws_size,
                              hipStream_t stream) {
    const float* v      = (const float*)d_in[0];
    const int*   action = (const int*)d_in[1];
    const float* W      = (const float*)d_in[2];
    float* out = (float*)d_out;
    const int batch = in_sizes[1];
    if (batch <= 0) return;

    if (batch > MAXB) {
        naive_vm<<<batch, 256, 0, stream>>>(v, W, action, out);
        return;
    }
    const int nblocks = NR_ACTIONS * 16;   // 1024: (action, 32-col pair); %8==0
    const size_t need = (size_t)batch * VEC * sizeof(ushort);

    if (ws_size >= need && ((size_t)batch * VEC) % 8 == 0) {
        ushort* vbf = (ushort*)d_ws;
        const int n8 = (int)((size_t)batch * VEC / 8);
        cvt_v_kernel<<<(n8 + 255) / 256, 256, 0, stream>>>(v, vbf, n8);
        grouped2<true><<<nblocks, 256, 0, stream>>>(v, vbf, action, W, out, batch);
    } else {
        grouped2<false><<<nblocks, 256, 0, stream>>>(v, (const ushort*)nullptr,
                                                     action, W, out, batch);
    }
}